// Round 9
// baseline (48.645 us; speedup 1.0000x reference)
//
#include <hip/hip_runtime.h>
#include <hip/hip_fp16.h>
#include <math.h>

#define KNN 8
#define CF 16
#define SRS 128
#define NRAYS 4096
#define NSAMP (NRAYS * SRS)   // 524288

typedef unsigned long long u64;

// ---- pass 1: hproj[p] = points_feat[p] @ [w_rgb | w_sigma]  (4 fp16 = 8 B) ----
__global__ __launch_bounds__(256) void hproj_kernel(
    const float* __restrict__ pf,        // [npts, 16]
    const float* __restrict__ w_rgb,     // [16, 3]
    const float* __restrict__ w_sigma,   // [16, 1]
    uint2* __restrict__ hproj, int npts)
{
    const int p = blockIdx.x * blockDim.x + threadIdx.x;
    if (p >= npts) return;
    const float4* r4 = (const float4*)(pf + (long long)p * CF);
    const float4 a = r4[0], b = r4[1], c = r4[2], d = r4[3];
    const float f[CF] = {a.x, a.y, a.z, a.w, b.x, b.y, b.z, b.w,
                         c.x, c.y, c.z, c.w, d.x, d.y, d.z, d.w};
    float h0 = 0.f, h1 = 0.f, h2 = 0.f, h3 = 0.f;
#pragma unroll
    for (int k = 0; k < CF; ++k) {
        const float fc = f[k];
        h0 = fmaf(fc, w_rgb[k * 3 + 0], h0);
        h1 = fmaf(fc, w_rgb[k * 3 + 1], h1);
        h2 = fmaf(fc, w_rgb[k * 3 + 2], h2);
        h3 = fmaf(fc, w_sigma[k], h3);
    }
    union { __half2 h[2]; uint2 u; } pk;
    pk.h[0] = __floats2half2_rn(h0, h1);
    pk.h[1] = __floats2half2_rn(h2, h3);
    hproj[p] = pk.u;
}

// ---- pass 2: pure gather machine. 1 thread = 1 sample. ----
// Writes {rgb0, rgb1, rgb2, alpha} per sample.
__global__ __launch_bounds__(256) void gather_kernel(
    const uint2* __restrict__ hproj,     // [npts] packed fp16 {h0,h1,h2,h3}
    const int*   __restrict__ indices,   // [NSAMP, 8]
    const float* __restrict__ dists,     // [NSAMP, 8]
    const float* __restrict__ delta,     // [NSAMP]
    float4* __restrict__ smp)            // [NSAMP] {r0,r1,r2,alpha}
{
    const int n = blockIdx.x * blockDim.x + threadIdx.x;
    if (n >= NSAMP) return;

    // ---- stream loads (non-temporal) ----
    const u64* ip = (const u64*)(indices + (long long)n * KNN);
    const u64* dp = (const u64*)(dists   + (long long)n * KNN);
    u64 iu[4], du[4];
#pragma unroll
    for (int m = 0; m < 4; ++m) {
        iu[m] = __builtin_nontemporal_load(ip + m);
        du[m] = __builtin_nontemporal_load(dp + m);
    }
    const float del = __builtin_nontemporal_load(delta + n);

    // ---- 8 independent 8-B table gathers, all issued before any use ----
    int idx[KNN];
#pragma unroll
    for (int m = 0; m < 4; ++m) {
        idx[2 * m]     = (int)(iu[m] & 0xffffffffull);
        idx[2 * m + 1] = (int)(iu[m] >> 32);
    }
    uint2 g[KNN];
#pragma unroll
    for (int k = 0; k < KNN; ++k) g[k] = hproj[(unsigned)idx[k]];

    // ---- weights (overlaps gather latency) ----
    float wk[KNN];
#pragma unroll
    for (int m = 0; m < 4; ++m) {
        wk[2 * m]     = 1.0f / (__uint_as_float((unsigned)(du[m] & 0xffffffffull)) + 1e-7f);
        wk[2 * m + 1] = 1.0f / (__uint_as_float((unsigned)(du[m] >> 32)) + 1e-7f);
    }
    float wsum = 0.f;
#pragma unroll
    for (int k = 0; k < KNN; ++k) wsum += wk[k];
    const float winv = 1.0f / wsum;

    float h0 = 0.f, h1 = 0.f, h2 = 0.f, h3 = 0.f;
#pragma unroll
    for (int k = 0; k < KNN; ++k) {
        union { unsigned u; __half2 h; } c0, c1;
        c0.u = g[k].x; c1.u = g[k].y;
        const float2 lo = __half22float2(c0.h);
        const float2 hi = __half22float2(c1.h);
        h0 = fmaf(wk[k], lo.x, h0);
        h1 = fmaf(wk[k], lo.y, h1);
        h2 = fmaf(wk[k], hi.x, h2);
        h3 = fmaf(wk[k], hi.y, h3);
    }

    float4 o;
    o.x = 1.0f / (1.0f + expf(-h0 * winv));
    o.y = 1.0f / (1.0f + expf(-h1 * winv));
    o.z = 1.0f / (1.0f + expf(-h2 * winv));
    const float sg = fmaxf(h3 * winv, 0.0f);
    o.w = 1.0f - expf(-sg * del);
    smp[n] = o;
}

// ---- pass 3: per-ray volumetric compositing (scan + reductions) ----
__global__ __launch_bounds__(SRS) void composite_kernel(
    const float4* __restrict__ smp,      // [NSAMP] {r0,r1,r2,alpha}
    const float*  __restrict__ z_vals,   // [NSAMP]
    float* __restrict__ out)             // [NRAYS, 5]
{
    const int ray  = blockIdx.x;
    const int t    = threadIdx.x;        // sample (0..127)
    const int lane = t & 63;
    const int wid  = t >> 6;
    const long long n = (long long)ray * SRS + t;

    __shared__ float s_wavetot;
    __shared__ float s_red[2][5];

    const float4 v  = smp[n];
    const float  zv = __builtin_nontemporal_load(z_vals + n);
    const float alpha = v.w;

    float p = 1.0f - alpha + 1e-10f;
#pragma unroll
    for (int off = 1; off < 64; off <<= 1) {
        const float u = __shfl_up(p, off, 64);
        if (lane >= off) p *= u;
    }
    if (wid == 0 && lane == 63) s_wavetot = p;
    __syncthreads();

    const float pm1 = __shfl_up(p, 1, 64);
    float excl = (lane == 0) ? 1.0f : pm1;
    if (wid == 1) excl *= s_wavetot;
    const float wts = alpha * excl;

    float v0 = wts * v.x;
    float v1 = wts * v.y;
    float v2 = wts * v.z;
    float v3 = wts * zv;
    float v4 = wts;
#pragma unroll
    for (int off = 32; off >= 1; off >>= 1) {
        v0 += __shfl_down(v0, off, 64);
        v1 += __shfl_down(v1, off, 64);
        v2 += __shfl_down(v2, off, 64);
        v3 += __shfl_down(v3, off, 64);
        v4 += __shfl_down(v4, off, 64);
    }
    if (lane == 0) {
        s_red[wid][0] = v0;
        s_red[wid][1] = v1;
        s_red[wid][2] = v2;
        s_red[wid][3] = v3;
        s_red[wid][4] = v4;
    }
    __syncthreads();

    if (t == 0) {
        const float q0  = s_red[0][0] + s_red[1][0];
        const float q1  = s_red[0][1] + s_red[1][1];
        const float q2  = s_red[0][2] + s_red[1][2];
        const float dep = s_red[0][3] + s_red[1][3];
        const float acc = s_red[0][4] + s_red[1][4];
        const float bg  = 1.0f - acc;
        float* o = out + (long long)ray * 5;
        o[0] = q0 + bg;
        o[1] = q1 + bg;
        o[2] = q2 + bg;
        o[3] = dep;
        o[4] = acc;
    }
}

// ---- fallback: direct fp32 gather path (if ws too small) ----
__global__ __launch_bounds__(512) void pvr_fused_f32(
    const float* __restrict__ points_feat,
    const int*   __restrict__ indices,
    const float* __restrict__ dists,
    const float* __restrict__ w_rgb,
    const float* __restrict__ w_sigma,
    const float* __restrict__ delta,
    const float* __restrict__ z_vals,
    float* __restrict__ out)
{
    const int ray = blockIdx.x;
    const int t   = threadIdx.x;
    const int s   = t >> 2;
    const int j   = t & 3;
    const long long n = (long long)ray * SRS + s;

    __shared__ float s_wrgb[CF * 3];
    __shared__ float s_wsig[CF];
    __shared__ float s_sig[SRS];
    __shared__ float s_rgbv[3][SRS];
    __shared__ float s_wavetot;
    __shared__ float s_red[2][5];

    if (t < CF * 3)            s_wrgb[t] = w_rgb[t];
    else if (t < CF * 3 + CF)  s_wsig[t - CF * 3] = w_sigma[t - CF * 3];

    const int2   i2 = ((const int2*)indices)[n * 4 + j];
    const float2 d2 = ((const float2*)dists)[n * 4 + j];

    float w0 = 1.0f / (d2.x + 1e-7f);
    float w1 = 1.0f / (d2.y + 1e-7f);
    float wsum = w0 + w1;
    wsum += __shfl_xor(wsum, 1);
    wsum += __shfl_xor(wsum, 2);
    const float winv = 1.0f / wsum;

    int   idxk[KNN];
    float wk[KNN];
#pragma unroll
    for (int m = 0; m < 4; ++m) {
        idxk[2 * m]     = __shfl(i2.x, m, 4);
        idxk[2 * m + 1] = __shfl(i2.y, m, 4);
        wk[2 * m]       = __shfl(w0, m, 4);
        wk[2 * m + 1]   = __shfl(w1, m, 4);
    }

    const float4* pf4 = (const float4*)points_feat;
    float4 r[KNN];
#pragma unroll
    for (int k = 0; k < KNN; ++k)
        r[k] = pf4[(long long)idxk[k] * 4 + j];

    float4 f = make_float4(0.f, 0.f, 0.f, 0.f);
#pragma unroll
    for (int k = 0; k < KNN; ++k) {
        f.x = fmaf(wk[k], r[k].x, f.x);
        f.y = fmaf(wk[k], r[k].y, f.y);
        f.z = fmaf(wk[k], r[k].z, f.z);
        f.w = fmaf(wk[k], r[k].w, f.w);
    }

    __syncthreads();

    float pr0 = 0.f, pr1 = 0.f, pr2 = 0.f, ps = 0.f;
    {
        const float fv[4] = {f.x, f.y, f.z, f.w};
#pragma unroll
        for (int m = 0; m < 4; ++m) {
            const int c = 4 * j + m;
            pr0 = fmaf(fv[m], s_wrgb[c * 3 + 0], pr0);
            pr1 = fmaf(fv[m], s_wrgb[c * 3 + 1], pr1);
            pr2 = fmaf(fv[m], s_wrgb[c * 3 + 2], pr2);
            ps  = fmaf(fv[m], s_wsig[c], ps);
        }
    }
    pr0 += __shfl_xor(pr0, 1); pr0 += __shfl_xor(pr0, 2);
    pr1 += __shfl_xor(pr1, 1); pr1 += __shfl_xor(pr1, 2);
    pr2 += __shfl_xor(pr2, 1); pr2 += __shfl_xor(pr2, 2);
    ps  += __shfl_xor(ps, 1);  ps  += __shfl_xor(ps, 2);

    if (j == 0) {
        s_sig[s]     = ps * winv;
        s_rgbv[0][s] = 1.0f / (1.0f + expf(-pr0 * winv));
        s_rgbv[1][s] = 1.0f / (1.0f + expf(-pr1 * winv));
        s_rgbv[2][s] = 1.0f / (1.0f + expf(-pr2 * winv));
    }
    __syncthreads();

    float p = 0.0f, alpha = 0.0f, zv = 0.0f;
    float r0 = 0.0f, r1 = 0.0f, r2 = 0.0f;
    const int lane = t & 63;
    const int wid  = t >> 6;
    if (t < SRS) {
        const long long m = (long long)ray * SRS + t;
        const float del = __builtin_nontemporal_load(delta  + m);
        zv              = __builtin_nontemporal_load(z_vals + m);
        const float sg  = fmaxf(s_sig[t], 0.0f);
        alpha = 1.0f - expf(-sg * del);
        r0 = s_rgbv[0][t]; r1 = s_rgbv[1][t]; r2 = s_rgbv[2][t];

        p = 1.0f - alpha + 1e-10f;
#pragma unroll
        for (int off = 1; off < 64; off <<= 1) {
            float v = __shfl_up(p, off, 64);
            if (lane >= off) p *= v;
        }
        if (wid == 0 && lane == 63) s_wavetot = p;
    }
    __syncthreads();

    if (t < SRS) {
        float pm1  = __shfl_up(p, 1, 64);
        float excl = (lane == 0) ? 1.0f : pm1;
        if (wid == 1) excl *= s_wavetot;
        const float wts = alpha * excl;

        float v0 = wts * r0;
        float v1 = wts * r1;
        float v2 = wts * r2;
        float v3 = wts * zv;
        float v4 = wts;
#pragma unroll
        for (int off = 32; off >= 1; off >>= 1) {
            v0 += __shfl_down(v0, off, 64);
            v1 += __shfl_down(v1, off, 64);
            v2 += __shfl_down(v2, off, 64);
            v3 += __shfl_down(v3, off, 64);
            v4 += __shfl_down(v4, off, 64);
        }
        if (lane == 0) {
            s_red[wid][0] = v0;
            s_red[wid][1] = v1;
            s_red[wid][2] = v2;
            s_red[wid][3] = v3;
            s_red[wid][4] = v4;
        }
    }
    __syncthreads();

    if (t == 0) {
        float q0  = s_red[0][0] + s_red[1][0];
        float q1  = s_red[0][1] + s_red[1][1];
        float q2  = s_red[0][2] + s_red[1][2];
        float dep = s_red[0][3] + s_red[1][3];
        float acc = s_red[0][4] + s_red[1][4];
        float bg  = 1.0f - acc;
        float* o = out + (long long)ray * 5;
        o[0] = q0 + bg;
        o[1] = q1 + bg;
        o[2] = q2 + bg;
        o[3] = dep;
        o[4] = acc;
    }
}

extern "C" void kernel_launch(void* const* d_in, const int* in_sizes, int n_in,
                              void* d_out, int out_size, void* d_ws, size_t ws_size,
                              hipStream_t stream) {
    const float* points_feat = (const float*)d_in[0];
    const int*   indices     = (const int*)d_in[1];
    const float* dists       = (const float*)d_in[2];
    const float* w_rgb       = (const float*)d_in[3];
    const float* w_sigma     = (const float*)d_in[4];
    const float* delta       = (const float*)d_in[5];
    const float* z_vals      = (const float*)d_in[6];
    float* out = (float*)d_out;

    const int npts = in_sizes[0] / CF;
    const size_t tbl_bytes = (size_t)npts * sizeof(uint2);      // 4 MB
    const size_t smp_bytes = (size_t)NSAMP * sizeof(float4);    // 8.4 MB
    if (ws_size >= tbl_bytes + smp_bytes) {
        uint2*  tbl = (uint2*)d_ws;
        float4* smp = (float4*)((char*)d_ws + tbl_bytes);
        hproj_kernel<<<(npts + 255) / 256, 256, 0, stream>>>(
            points_feat, w_rgb, w_sigma, tbl, npts);
        gather_kernel<<<(NSAMP + 255) / 256, 256, 0, stream>>>(
            tbl, indices, dists, delta, smp);
        composite_kernel<<<NRAYS, SRS, 0, stream>>>(smp, z_vals, out);
    } else {
        pvr_fused_f32<<<NRAYS, 512, 0, stream>>>(
            points_feat, indices, dists, w_rgb, w_sigma, delta, z_vals, out);
    }
}

// Round 10
// 47.626 us; speedup vs baseline: 1.0214x; 1.0214x over previous
//
#include <hip/hip_runtime.h>
#include <hip/hip_fp16.h>
#include <math.h>

#define KNN 8
#define CF 16
#define SRS 128
#define NRAYS 4096
#define TPB 128

typedef unsigned long long u64;

// ---- pass 1: hproj[p] = points_feat[p] @ [w_rgb | w_sigma]  (4 fp16 = 8 B) ----
// Non-temporal reads: don't let the 32 MB stream evict the table being written.
__global__ __launch_bounds__(256) void hproj_kernel(
    const float* __restrict__ pf,        // [npts, 16]
    const float* __restrict__ w_rgb,     // [16, 3]
    const float* __restrict__ w_sigma,   // [16, 1]
    uint2* __restrict__ hproj, int npts)
{
    const int p = blockIdx.x * blockDim.x + threadIdx.x;
    if (p >= npts) return;
    const u64* r8 = (const u64*)(pf + (long long)p * CF);
    u64 q[8];
#pragma unroll
    for (int m = 0; m < 8; ++m) q[m] = __builtin_nontemporal_load(r8 + m);
    float f[CF];
#pragma unroll
    for (int m = 0; m < 8; ++m) {
        f[2 * m]     = __uint_as_float((unsigned)(q[m] & 0xffffffffull));
        f[2 * m + 1] = __uint_as_float((unsigned)(q[m] >> 32));
    }
    float h0 = 0.f, h1 = 0.f, h2 = 0.f, h3 = 0.f;
#pragma unroll
    for (int k = 0; k < CF; ++k) {
        const float fc = f[k];
        h0 = fmaf(fc, w_rgb[k * 3 + 0], h0);
        h1 = fmaf(fc, w_rgb[k * 3 + 1], h1);
        h2 = fmaf(fc, w_rgb[k * 3 + 2], h2);
        h3 = fmaf(fc, w_sigma[k], h3);
    }
    union { __half2 h[2]; uint2 u; } pk;
    pk.h[0] = __floats2half2_rn(h0, h1);
    pk.h[1] = __floats2half2_rn(h2, h3);
    hproj[p] = pk.u;
}

// ---- main: 2 rays/block, 1 thread = 1 sample per ray, 16 gathers in flight ----
__global__ __launch_bounds__(TPB, 4) void pvr_main2(
    const uint2* __restrict__ hproj,     // [npts] packed {rgb0,rgb1,rgb2,sig} fp16
    const int*   __restrict__ indices,   // [N, 8]
    const float* __restrict__ dists,     // [N, 8]
    const float* __restrict__ delta,     // [R, SR]
    const float* __restrict__ z_vals,    // [R, SR]
    float* __restrict__ out)             // [R, 5]
{
    const int t    = threadIdx.x;        // sample index (0..127)
    const int lane = t & 63;
    const int wid  = t >> 6;
    const int rayA = blockIdx.x * 2;
    const long long nA = (long long)rayA * SRS + t;
    const long long nB = nA + SRS;

    __shared__ float s_wtot[2];
    __shared__ float s_red[2][2][5];     // [wave][ray][5]

    // ---- all stream loads issued first (non-temporal) ----
    const u64* ipA = (const u64*)(indices + nA * KNN);
    const u64* dpA = (const u64*)(dists   + nA * KNN);
    const u64* ipB = (const u64*)(indices + nB * KNN);
    const u64* dpB = (const u64*)(dists   + nB * KNN);
    u64 iuA[4], duA[4], iuB[4], duB[4];
#pragma unroll
    for (int m = 0; m < 4; ++m) {
        iuA[m] = __builtin_nontemporal_load(ipA + m);
        iuB[m] = __builtin_nontemporal_load(ipB + m);
        duA[m] = __builtin_nontemporal_load(dpA + m);
        duB[m] = __builtin_nontemporal_load(dpB + m);
    }
    const float delA = __builtin_nontemporal_load(delta  + nA);
    const float zvA  = __builtin_nontemporal_load(z_vals + nA);
    const float delB = __builtin_nontemporal_load(delta  + nB);
    const float zvB  = __builtin_nontemporal_load(z_vals + nB);

    // ---- 16 independent table gathers, all in flight ----
    int idxA[KNN], idxB[KNN];
#pragma unroll
    for (int m = 0; m < 4; ++m) {
        idxA[2 * m]     = (int)(iuA[m] & 0xffffffffull);
        idxA[2 * m + 1] = (int)(iuA[m] >> 32);
        idxB[2 * m]     = (int)(iuB[m] & 0xffffffffull);
        idxB[2 * m + 1] = (int)(iuB[m] >> 32);
    }
    uint2 gA[KNN], gB[KNN];
#pragma unroll
    for (int k = 0; k < KNN; ++k) gA[k] = hproj[(unsigned)idxA[k]];
#pragma unroll
    for (int k = 0; k < KNN; ++k) gB[k] = hproj[(unsigned)idxB[k]];

    // ---- weights (fully per-thread; overlaps gather latency) ----
    float wkA[KNN], wkB[KNN];
#pragma unroll
    for (int m = 0; m < 4; ++m) {
        wkA[2 * m]     = 1.0f / (__uint_as_float((unsigned)(duA[m] & 0xffffffffull)) + 1e-7f);
        wkA[2 * m + 1] = 1.0f / (__uint_as_float((unsigned)(duA[m] >> 32)) + 1e-7f);
        wkB[2 * m]     = 1.0f / (__uint_as_float((unsigned)(duB[m] & 0xffffffffull)) + 1e-7f);
        wkB[2 * m + 1] = 1.0f / (__uint_as_float((unsigned)(duB[m] >> 32)) + 1e-7f);
    }
    float wsA = 0.f, wsB = 0.f;
#pragma unroll
    for (int k = 0; k < KNN; ++k) { wsA += wkA[k]; wsB += wkB[k]; }
    const float winvA = 1.0f / wsA;
    const float winvB = 1.0f / wsB;

    // ---- accumulate h for both samples ----
    float hA0 = 0.f, hA1 = 0.f, hA2 = 0.f, hA3 = 0.f;
    float hB0 = 0.f, hB1 = 0.f, hB2 = 0.f, hB3 = 0.f;
#pragma unroll
    for (int k = 0; k < KNN; ++k) {
        union { unsigned u; __half2 h; } c0, c1;
        c0.u = gA[k].x; c1.u = gA[k].y;
        const float2 lo = __half22float2(c0.h);
        const float2 hi = __half22float2(c1.h);
        hA0 = fmaf(wkA[k], lo.x, hA0);
        hA1 = fmaf(wkA[k], lo.y, hA1);
        hA2 = fmaf(wkA[k], hi.x, hA2);
        hA3 = fmaf(wkA[k], hi.y, hA3);
    }
#pragma unroll
    for (int k = 0; k < KNN; ++k) {
        union { unsigned u; __half2 h; } c0, c1;
        c0.u = gB[k].x; c1.u = gB[k].y;
        const float2 lo = __half22float2(c0.h);
        const float2 hi = __half22float2(c1.h);
        hB0 = fmaf(wkB[k], lo.x, hB0);
        hB1 = fmaf(wkB[k], lo.y, hB1);
        hB2 = fmaf(wkB[k], hi.x, hB2);
        hB3 = fmaf(wkB[k], hi.y, hB3);
    }

    const float rA0 = 1.0f / (1.0f + __expf(-hA0 * winvA));
    const float rA1 = 1.0f / (1.0f + __expf(-hA1 * winvA));
    const float rA2 = 1.0f / (1.0f + __expf(-hA2 * winvA));
    const float sgA = fmaxf(hA3 * winvA, 0.0f);
    const float rB0 = 1.0f / (1.0f + __expf(-hB0 * winvB));
    const float rB1 = 1.0f / (1.0f + __expf(-hB1 * winvB));
    const float rB2 = 1.0f / (1.0f + __expf(-hB2 * winvB));
    const float sgB = fmaxf(hB3 * winvB, 0.0f);

    const float alphaA = 1.0f - __expf(-sgA * delA);
    const float alphaB = 1.0f - __expf(-sgB * delB);

    // ---- dual prefix products (interleaved chains) ----
    float pA = 1.0f - alphaA + 1e-10f;
    float pB = 1.0f - alphaB + 1e-10f;
#pragma unroll
    for (int off = 1; off < 64; off <<= 1) {
        const float vA = __shfl_up(pA, off, 64);
        const float vB = __shfl_up(pB, off, 64);
        if (lane >= off) { pA *= vA; pB *= vB; }
    }
    if (wid == 0 && lane == 63) { s_wtot[0] = pA; s_wtot[1] = pB; }
    __syncthreads();

    const float pm1A = __shfl_up(pA, 1, 64);
    const float pm1B = __shfl_up(pB, 1, 64);
    float exclA = (lane == 0) ? 1.0f : pm1A;
    float exclB = (lane == 0) ? 1.0f : pm1B;
    if (wid == 1) { exclA *= s_wtot[0]; exclB *= s_wtot[1]; }
    const float wtsA = alphaA * exclA;
    const float wtsB = alphaB * exclB;

    // ---- per-ray reductions (10 chains interleaved) ----
    float a0 = wtsA * rA0, a1 = wtsA * rA1, a2 = wtsA * rA2, a3 = wtsA * zvA, a4 = wtsA;
    float b0 = wtsB * rB0, b1 = wtsB * rB1, b2 = wtsB * rB2, b3 = wtsB * zvB, b4 = wtsB;
#pragma unroll
    for (int off = 32; off >= 1; off >>= 1) {
        a0 += __shfl_down(a0, off, 64);
        a1 += __shfl_down(a1, off, 64);
        a2 += __shfl_down(a2, off, 64);
        a3 += __shfl_down(a3, off, 64);
        a4 += __shfl_down(a4, off, 64);
        b0 += __shfl_down(b0, off, 64);
        b1 += __shfl_down(b1, off, 64);
        b2 += __shfl_down(b2, off, 64);
        b3 += __shfl_down(b3, off, 64);
        b4 += __shfl_down(b4, off, 64);
    }
    if (lane == 0) {
        s_red[wid][0][0] = a0; s_red[wid][0][1] = a1; s_red[wid][0][2] = a2;
        s_red[wid][0][3] = a3; s_red[wid][0][4] = a4;
        s_red[wid][1][0] = b0; s_red[wid][1][1] = b1; s_red[wid][1][2] = b2;
        s_red[wid][1][3] = b3; s_red[wid][1][4] = b4;
    }
    __syncthreads();

    if (t < 2) {   // thread 0 writes ray A, thread 1 writes ray B
        const float q0  = s_red[0][t][0] + s_red[1][t][0];
        const float q1  = s_red[0][t][1] + s_red[1][t][1];
        const float q2  = s_red[0][t][2] + s_red[1][t][2];
        const float dep = s_red[0][t][3] + s_red[1][t][3];
        const float acc = s_red[0][t][4] + s_red[1][t][4];
        const float bg  = 1.0f - acc;
        float* o = out + (long long)(rayA + t) * 5;
        o[0] = q0 + bg;
        o[1] = q1 + bg;
        o[2] = q2 + bg;
        o[3] = dep;
        o[4] = acc;
    }
}

// ---- fallback: direct fp32 gather path (if ws too small) ----
__global__ __launch_bounds__(512) void pvr_fused_f32(
    const float* __restrict__ points_feat,
    const int*   __restrict__ indices,
    const float* __restrict__ dists,
    const float* __restrict__ w_rgb,
    const float* __restrict__ w_sigma,
    const float* __restrict__ delta,
    const float* __restrict__ z_vals,
    float* __restrict__ out)
{
    const int ray = blockIdx.x;
    const int t   = threadIdx.x;
    const int s   = t >> 2;
    const int j   = t & 3;
    const long long n = (long long)ray * SRS + s;

    __shared__ float s_wrgb[CF * 3];
    __shared__ float s_wsig[CF];
    __shared__ float s_sig[SRS];
    __shared__ float s_rgbv[3][SRS];
    __shared__ float s_wavetot;
    __shared__ float s_red[2][5];

    if (t < CF * 3)            s_wrgb[t] = w_rgb[t];
    else if (t < CF * 3 + CF)  s_wsig[t - CF * 3] = w_sigma[t - CF * 3];

    const int2   i2 = ((const int2*)indices)[n * 4 + j];
    const float2 d2 = ((const float2*)dists)[n * 4 + j];

    float w0 = 1.0f / (d2.x + 1e-7f);
    float w1 = 1.0f / (d2.y + 1e-7f);
    float wsum = w0 + w1;
    wsum += __shfl_xor(wsum, 1);
    wsum += __shfl_xor(wsum, 2);
    const float winv = 1.0f / wsum;

    int   idxk[KNN];
    float wk[KNN];
#pragma unroll
    for (int m = 0; m < 4; ++m) {
        idxk[2 * m]     = __shfl(i2.x, m, 4);
        idxk[2 * m + 1] = __shfl(i2.y, m, 4);
        wk[2 * m]       = __shfl(w0, m, 4);
        wk[2 * m + 1]   = __shfl(w1, m, 4);
    }

    const float4* pf4 = (const float4*)points_feat;
    float4 r[KNN];
#pragma unroll
    for (int k = 0; k < KNN; ++k)
        r[k] = pf4[(long long)idxk[k] * 4 + j];

    float4 f = make_float4(0.f, 0.f, 0.f, 0.f);
#pragma unroll
    for (int k = 0; k < KNN; ++k) {
        f.x = fmaf(wk[k], r[k].x, f.x);
        f.y = fmaf(wk[k], r[k].y, f.y);
        f.z = fmaf(wk[k], r[k].z, f.z);
        f.w = fmaf(wk[k], r[k].w, f.w);
    }

    __syncthreads();

    float pr0 = 0.f, pr1 = 0.f, pr2 = 0.f, ps = 0.f;
    {
        const float fv[4] = {f.x, f.y, f.z, f.w};
#pragma unroll
        for (int m = 0; m < 4; ++m) {
            const int c = 4 * j + m;
            pr0 = fmaf(fv[m], s_wrgb[c * 3 + 0], pr0);
            pr1 = fmaf(fv[m], s_wrgb[c * 3 + 1], pr1);
            pr2 = fmaf(fv[m], s_wrgb[c * 3 + 2], pr2);
            ps  = fmaf(fv[m], s_wsig[c], ps);
        }
    }
    pr0 += __shfl_xor(pr0, 1); pr0 += __shfl_xor(pr0, 2);
    pr1 += __shfl_xor(pr1, 1); pr1 += __shfl_xor(pr1, 2);
    pr2 += __shfl_xor(pr2, 1); pr2 += __shfl_xor(pr2, 2);
    ps  += __shfl_xor(ps, 1);  ps  += __shfl_xor(ps, 2);

    if (j == 0) {
        s_sig[s]     = ps * winv;
        s_rgbv[0][s] = 1.0f / (1.0f + expf(-pr0 * winv));
        s_rgbv[1][s] = 1.0f / (1.0f + expf(-pr1 * winv));
        s_rgbv[2][s] = 1.0f / (1.0f + expf(-pr2 * winv));
    }
    __syncthreads();

    float p = 0.0f, alpha = 0.0f, zv = 0.0f;
    float r0 = 0.0f, r1 = 0.0f, r2 = 0.0f;
    const int lane = t & 63;
    const int wid  = t >> 6;
    if (t < SRS) {
        const long long m = (long long)ray * SRS + t;
        const float del = __builtin_nontemporal_load(delta  + m);
        zv              = __builtin_nontemporal_load(z_vals + m);
        const float sg  = fmaxf(s_sig[t], 0.0f);
        alpha = 1.0f - expf(-sg * del);
        r0 = s_rgbv[0][t]; r1 = s_rgbv[1][t]; r2 = s_rgbv[2][t];

        p = 1.0f - alpha + 1e-10f;
#pragma unroll
        for (int off = 1; off < 64; off <<= 1) {
            float v = __shfl_up(p, off, 64);
            if (lane >= off) p *= v;
        }
        if (wid == 0 && lane == 63) s_wavetot = p;
    }
    __syncthreads();

    if (t < SRS) {
        float pm1  = __shfl_up(p, 1, 64);
        float excl = (lane == 0) ? 1.0f : pm1;
        if (wid == 1) excl *= s_wavetot;
        const float wts = alpha * excl;

        float v0 = wts * r0;
        float v1 = wts * r1;
        float v2 = wts * r2;
        float v3 = wts * zv;
        float v4 = wts;
#pragma unroll
        for (int off = 32; off >= 1; off >>= 1) {
            v0 += __shfl_down(v0, off, 64);
            v1 += __shfl_down(v1, off, 64);
            v2 += __shfl_down(v2, off, 64);
            v3 += __shfl_down(v3, off, 64);
            v4 += __shfl_down(v4, off, 64);
        }
        if (lane == 0) {
            s_red[wid][0] = v0;
            s_red[wid][1] = v1;
            s_red[wid][2] = v2;
            s_red[wid][3] = v3;
            s_red[wid][4] = v4;
        }
    }
    __syncthreads();

    if (t == 0) {
        float q0  = s_red[0][0] + s_red[1][0];
        float q1  = s_red[0][1] + s_red[1][1];
        float q2  = s_red[0][2] + s_red[1][2];
        float dep = s_red[0][3] + s_red[1][3];
        float acc = s_red[0][4] + s_red[1][4];
        float bg  = 1.0f - acc;
        float* o = out + (long long)ray * 5;
        o[0] = q0 + bg;
        o[1] = q1 + bg;
        o[2] = q2 + bg;
        o[3] = dep;
        o[4] = acc;
    }
}

extern "C" void kernel_launch(void* const* d_in, const int* in_sizes, int n_in,
                              void* d_out, int out_size, void* d_ws, size_t ws_size,
                              hipStream_t stream) {
    const float* points_feat = (const float*)d_in[0];
    const int*   indices     = (const int*)d_in[1];
    const float* dists       = (const float*)d_in[2];
    const float* w_rgb       = (const float*)d_in[3];
    const float* w_sigma     = (const float*)d_in[4];
    const float* delta       = (const float*)d_in[5];
    const float* z_vals      = (const float*)d_in[6];
    float* out = (float*)d_out;

    const int npts = in_sizes[0] / CF;
    const size_t need = (size_t)npts * sizeof(uint2);
    if (ws_size >= need) {
        hproj_kernel<<<(npts + 255) / 256, 256, 0, stream>>>(
            points_feat, w_rgb, w_sigma, (uint2*)d_ws, npts);
        pvr_main2<<<NRAYS / 2, TPB, 0, stream>>>(
            (const uint2*)d_ws, indices, dists, delta, z_vals, out);
    } else {
        pvr_fused_f32<<<NRAYS, 512, 0, stream>>>(
            points_feat, indices, dists, w_rgb, w_sigma, delta, z_vals, out);
    }
}

// Round 11
// 40.558 us; speedup vs baseline: 1.1994x; 1.1743x over previous
//
#include <hip/hip_runtime.h>
#include <hip/hip_fp16.h>
#include <math.h>

#define KNN 8
#define CF 16
#define SRS 128
#define NRAYS 4096
#define TPB 128

typedef unsigned long long u64;

// ---- pass 1: hproj[p] = points_feat[p] @ [w_rgb | w_sigma]  (4 fp16 = 8 B) ----
__global__ __launch_bounds__(256) void hproj_kernel(
    const float* __restrict__ pf,        // [npts, 16]
    const float* __restrict__ w_rgb,     // [16, 3]
    const float* __restrict__ w_sigma,   // [16, 1]
    uint2* __restrict__ hproj, int npts)
{
    const int p = blockIdx.x * blockDim.x + threadIdx.x;
    if (p >= npts) return;
    const float4* r4 = (const float4*)(pf + (long long)p * CF);
    const float4 a = r4[0], b = r4[1], c = r4[2], d = r4[3];
    const float f[CF] = {a.x, a.y, a.z, a.w, b.x, b.y, b.z, b.w,
                         c.x, c.y, c.z, c.w, d.x, d.y, d.z, d.w};
    float h0 = 0.f, h1 = 0.f, h2 = 0.f, h3 = 0.f;
#pragma unroll
    for (int k = 0; k < CF; ++k) {
        const float fc = f[k];
        h0 = fmaf(fc, w_rgb[k * 3 + 0], h0);
        h1 = fmaf(fc, w_rgb[k * 3 + 1], h1);
        h2 = fmaf(fc, w_rgb[k * 3 + 2], h2);
        h3 = fmaf(fc, w_sigma[k], h3);
    }
    union { __half2 h[2]; uint2 u; } pk;
    pk.h[0] = __floats2half2_rn(h0, h1);
    pk.h[1] = __floats2half2_rn(h2, h3);
    hproj[p] = pk.u;
}

// ---- main: 2 rays/block; gathers bypass L1 via agent-scope loads ----
__global__ __launch_bounds__(TPB, 4) void pvr_main2(
    const uint2* __restrict__ hproj,     // [npts] packed {rgb0,rgb1,rgb2,sig} fp16
    const int*   __restrict__ indices,   // [N, 8]
    const float* __restrict__ dists,     // [N, 8]
    const float* __restrict__ delta,     // [R, SR]
    const float* __restrict__ z_vals,    // [R, SR]
    float* __restrict__ out)             // [R, 5]
{
    const int t    = threadIdx.x;        // sample index (0..127)
    const int lane = t & 63;
    const int wid  = t >> 6;
    const int rayA = blockIdx.x * 2;
    const long long nA = (long long)rayA * SRS + t;
    const long long nB = nA + SRS;

    __shared__ float s_wtot[2];
    __shared__ float s_red[2][2][5];     // [wave][ray][5]

    // ---- all stream loads issued first (non-temporal) ----
    const u64* ipA = (const u64*)(indices + nA * KNN);
    const u64* dpA = (const u64*)(dists   + nA * KNN);
    const u64* ipB = (const u64*)(indices + nB * KNN);
    const u64* dpB = (const u64*)(dists   + nB * KNN);
    u64 iuA[4], duA[4], iuB[4], duB[4];
#pragma unroll
    for (int m = 0; m < 4; ++m) {
        iuA[m] = __builtin_nontemporal_load(ipA + m);
        iuB[m] = __builtin_nontemporal_load(ipB + m);
        duA[m] = __builtin_nontemporal_load(dpA + m);
        duB[m] = __builtin_nontemporal_load(dpB + m);
    }
    const float delA = __builtin_nontemporal_load(delta  + nA);
    const float zvA  = __builtin_nontemporal_load(z_vals + nA);
    const float delB = __builtin_nontemporal_load(delta  + nB);
    const float zvB  = __builtin_nontemporal_load(z_vals + nB);

    // ---- 16 independent table gathers, L1-bypassed, all in flight ----
    int idxA[KNN], idxB[KNN];
#pragma unroll
    for (int m = 0; m < 4; ++m) {
        idxA[2 * m]     = (int)(iuA[m] & 0xffffffffull);
        idxA[2 * m + 1] = (int)(iuA[m] >> 32);
        idxB[2 * m]     = (int)(iuB[m] & 0xffffffffull);
        idxB[2 * m + 1] = (int)(iuB[m] >> 32);
    }
    const u64* tbl = (const u64*)hproj;
    u64 gA[KNN], gB[KNN];
#pragma unroll
    for (int k = 0; k < KNN; ++k)
        gA[k] = __hip_atomic_load(tbl + (unsigned)idxA[k],
                                  __ATOMIC_RELAXED, __HIP_MEMORY_SCOPE_AGENT);
#pragma unroll
    for (int k = 0; k < KNN; ++k)
        gB[k] = __hip_atomic_load(tbl + (unsigned)idxB[k],
                                  __ATOMIC_RELAXED, __HIP_MEMORY_SCOPE_AGENT);

    // ---- weights (fully per-thread; overlaps gather latency) ----
    float wkA[KNN], wkB[KNN];
#pragma unroll
    for (int m = 0; m < 4; ++m) {
        wkA[2 * m]     = 1.0f / (__uint_as_float((unsigned)(duA[m] & 0xffffffffull)) + 1e-7f);
        wkA[2 * m + 1] = 1.0f / (__uint_as_float((unsigned)(duA[m] >> 32)) + 1e-7f);
        wkB[2 * m]     = 1.0f / (__uint_as_float((unsigned)(duB[m] & 0xffffffffull)) + 1e-7f);
        wkB[2 * m + 1] = 1.0f / (__uint_as_float((unsigned)(duB[m] >> 32)) + 1e-7f);
    }
    float wsA = 0.f, wsB = 0.f;
#pragma unroll
    for (int k = 0; k < KNN; ++k) { wsA += wkA[k]; wsB += wkB[k]; }
    const float winvA = 1.0f / wsA;
    const float winvB = 1.0f / wsB;

    // ---- accumulate h for both samples ----
    float hA0 = 0.f, hA1 = 0.f, hA2 = 0.f, hA3 = 0.f;
    float hB0 = 0.f, hB1 = 0.f, hB2 = 0.f, hB3 = 0.f;
#pragma unroll
    for (int k = 0; k < KNN; ++k) {
        union { unsigned u; __half2 h; } c0, c1;
        c0.u = (unsigned)(gA[k] & 0xffffffffull);
        c1.u = (unsigned)(gA[k] >> 32);
        const float2 lo = __half22float2(c0.h);
        const float2 hi = __half22float2(c1.h);
        hA0 = fmaf(wkA[k], lo.x, hA0);
        hA1 = fmaf(wkA[k], lo.y, hA1);
        hA2 = fmaf(wkA[k], hi.x, hA2);
        hA3 = fmaf(wkA[k], hi.y, hA3);
    }
#pragma unroll
    for (int k = 0; k < KNN; ++k) {
        union { unsigned u; __half2 h; } c0, c1;
        c0.u = (unsigned)(gB[k] & 0xffffffffull);
        c1.u = (unsigned)(gB[k] >> 32);
        const float2 lo = __half22float2(c0.h);
        const float2 hi = __half22float2(c1.h);
        hB0 = fmaf(wkB[k], lo.x, hB0);
        hB1 = fmaf(wkB[k], lo.y, hB1);
        hB2 = fmaf(wkB[k], hi.x, hB2);
        hB3 = fmaf(wkB[k], hi.y, hB3);
    }

    const float rA0 = 1.0f / (1.0f + expf(-hA0 * winvA));
    const float rA1 = 1.0f / (1.0f + expf(-hA1 * winvA));
    const float rA2 = 1.0f / (1.0f + expf(-hA2 * winvA));
    const float sgA = fmaxf(hA3 * winvA, 0.0f);
    const float rB0 = 1.0f / (1.0f + expf(-hB0 * winvB));
    const float rB1 = 1.0f / (1.0f + expf(-hB1 * winvB));
    const float rB2 = 1.0f / (1.0f + expf(-hB2 * winvB));
    const float sgB = fmaxf(hB3 * winvB, 0.0f);

    const float alphaA = 1.0f - expf(-sgA * delA);
    const float alphaB = 1.0f - expf(-sgB * delB);

    // ---- dual prefix products (interleaved chains) ----
    float pA = 1.0f - alphaA + 1e-10f;
    float pB = 1.0f - alphaB + 1e-10f;
#pragma unroll
    for (int off = 1; off < 64; off <<= 1) {
        const float vA = __shfl_up(pA, off, 64);
        const float vB = __shfl_up(pB, off, 64);
        if (lane >= off) { pA *= vA; pB *= vB; }
    }
    if (wid == 0 && lane == 63) { s_wtot[0] = pA; s_wtot[1] = pB; }
    __syncthreads();

    const float pm1A = __shfl_up(pA, 1, 64);
    const float pm1B = __shfl_up(pB, 1, 64);
    float exclA = (lane == 0) ? 1.0f : pm1A;
    float exclB = (lane == 0) ? 1.0f : pm1B;
    if (wid == 1) { exclA *= s_wtot[0]; exclB *= s_wtot[1]; }
    const float wtsA = alphaA * exclA;
    const float wtsB = alphaB * exclB;

    // ---- per-ray reductions (10 chains interleaved) ----
    float a0 = wtsA * rA0, a1 = wtsA * rA1, a2 = wtsA * rA2, a3 = wtsA * zvA, a4 = wtsA;
    float b0 = wtsB * rB0, b1 = wtsB * rB1, b2 = wtsB * rB2, b3 = wtsB * zvB, b4 = wtsB;
#pragma unroll
    for (int off = 32; off >= 1; off >>= 1) {
        a0 += __shfl_down(a0, off, 64);
        a1 += __shfl_down(a1, off, 64);
        a2 += __shfl_down(a2, off, 64);
        a3 += __shfl_down(a3, off, 64);
        a4 += __shfl_down(a4, off, 64);
        b0 += __shfl_down(b0, off, 64);
        b1 += __shfl_down(b1, off, 64);
        b2 += __shfl_down(b2, off, 64);
        b3 += __shfl_down(b3, off, 64);
        b4 += __shfl_down(b4, off, 64);
    }
    if (lane == 0) {
        s_red[wid][0][0] = a0; s_red[wid][0][1] = a1; s_red[wid][0][2] = a2;
        s_red[wid][0][3] = a3; s_red[wid][0][4] = a4;
        s_red[wid][1][0] = b0; s_red[wid][1][1] = b1; s_red[wid][1][2] = b2;
        s_red[wid][1][3] = b3; s_red[wid][1][4] = b4;
    }
    __syncthreads();

    if (t < 2) {   // thread 0 writes ray A, thread 1 writes ray B
        const float q0  = s_red[0][t][0] + s_red[1][t][0];
        const float q1  = s_red[0][t][1] + s_red[1][t][1];
        const float q2  = s_red[0][t][2] + s_red[1][t][2];
        const float dep = s_red[0][t][3] + s_red[1][t][3];
        const float acc = s_red[0][t][4] + s_red[1][t][4];
        const float bg  = 1.0f - acc;
        float* o = out + (long long)(rayA + t) * 5;
        o[0] = q0 + bg;
        o[1] = q1 + bg;
        o[2] = q2 + bg;
        o[3] = dep;
        o[4] = acc;
    }
}

// ---- fallback: direct fp32 gather path (if ws too small) ----
__global__ __launch_bounds__(512) void pvr_fused_f32(
    const float* __restrict__ points_feat,
    const int*   __restrict__ indices,
    const float* __restrict__ dists,
    const float* __restrict__ w_rgb,
    const float* __restrict__ w_sigma,
    const float* __restrict__ delta,
    const float* __restrict__ z_vals,
    float* __restrict__ out)
{
    const int ray = blockIdx.x;
    const int t   = threadIdx.x;
    const int s   = t >> 2;
    const int j   = t & 3;
    const long long n = (long long)ray * SRS + s;

    __shared__ float s_wrgb[CF * 3];
    __shared__ float s_wsig[CF];
    __shared__ float s_sig[SRS];
    __shared__ float s_rgbv[3][SRS];
    __shared__ float s_wavetot;
    __shared__ float s_red[2][5];

    if (t < CF * 3)            s_wrgb[t] = w_rgb[t];
    else if (t < CF * 3 + CF)  s_wsig[t - CF * 3] = w_sigma[t - CF * 3];

    const int2   i2 = ((const int2*)indices)[n * 4 + j];
    const float2 d2 = ((const float2*)dists)[n * 4 + j];

    float w0 = 1.0f / (d2.x + 1e-7f);
    float w1 = 1.0f / (d2.y + 1e-7f);
    float wsum = w0 + w1;
    wsum += __shfl_xor(wsum, 1);
    wsum += __shfl_xor(wsum, 2);
    const float winv = 1.0f / wsum;

    int   idxk[KNN];
    float wk[KNN];
#pragma unroll
    for (int m = 0; m < 4; ++m) {
        idxk[2 * m]     = __shfl(i2.x, m, 4);
        idxk[2 * m + 1] = __shfl(i2.y, m, 4);
        wk[2 * m]       = __shfl(w0, m, 4);
        wk[2 * m + 1]   = __shfl(w1, m, 4);
    }

    const float4* pf4 = (const float4*)points_feat;
    float4 r[KNN];
#pragma unroll
    for (int k = 0; k < KNN; ++k)
        r[k] = pf4[(long long)idxk[k] * 4 + j];

    float4 f = make_float4(0.f, 0.f, 0.f, 0.f);
#pragma unroll
    for (int k = 0; k < KNN; ++k) {
        f.x = fmaf(wk[k], r[k].x, f.x);
        f.y = fmaf(wk[k], r[k].y, f.y);
        f.z = fmaf(wk[k], r[k].z, f.z);
        f.w = fmaf(wk[k], r[k].w, f.w);
    }

    __syncthreads();

    float pr0 = 0.f, pr1 = 0.f, pr2 = 0.f, ps = 0.f;
    {
        const float fv[4] = {f.x, f.y, f.z, f.w};
#pragma unroll
        for (int m = 0; m < 4; ++m) {
            const int c = 4 * j + m;
            pr0 = fmaf(fv[m], s_wrgb[c * 3 + 0], pr0);
            pr1 = fmaf(fv[m], s_wrgb[c * 3 + 1], pr1);
            pr2 = fmaf(fv[m], s_wrgb[c * 3 + 2], pr2);
            ps  = fmaf(fv[m], s_wsig[c], ps);
        }
    }
    pr0 += __shfl_xor(pr0, 1); pr0 += __shfl_xor(pr0, 2);
    pr1 += __shfl_xor(pr1, 1); pr1 += __shfl_xor(pr1, 2);
    pr2 += __shfl_xor(pr2, 1); pr2 += __shfl_xor(pr2, 2);
    ps  += __shfl_xor(ps, 1);  ps  += __shfl_xor(ps, 2);

    if (j == 0) {
        s_sig[s]     = ps * winv;
        s_rgbv[0][s] = 1.0f / (1.0f + expf(-pr0 * winv));
        s_rgbv[1][s] = 1.0f / (1.0f + expf(-pr1 * winv));
        s_rgbv[2][s] = 1.0f / (1.0f + expf(-pr2 * winv));
    }
    __syncthreads();

    float p = 0.0f, alpha = 0.0f, zv = 0.0f;
    float r0 = 0.0f, r1 = 0.0f, r2 = 0.0f;
    const int lane = t & 63;
    const int wid  = t >> 6;
    if (t < SRS) {
        const long long m = (long long)ray * SRS + t;
        const float del = __builtin_nontemporal_load(delta  + m);
        zv              = __builtin_nontemporal_load(z_vals + m);
        const float sg  = fmaxf(s_sig[t], 0.0f);
        alpha = 1.0f - expf(-sg * del);
        r0 = s_rgbv[0][t]; r1 = s_rgbv[1][t]; r2 = s_rgbv[2][t];

        p = 1.0f - alpha + 1e-10f;
#pragma unroll
        for (int off = 1; off < 64; off <<= 1) {
            float v = __shfl_up(p, off, 64);
            if (lane >= off) p *= v;
        }
        if (wid == 0 && lane == 63) s_wavetot = p;
    }
    __syncthreads();

    if (t < SRS) {
        float pm1  = __shfl_up(p, 1, 64);
        float excl = (lane == 0) ? 1.0f : pm1;
        if (wid == 1) excl *= s_wavetot;
        const float wts = alpha * excl;

        float v0 = wts * r0;
        float v1 = wts * r1;
        float v2 = wts * r2;
        float v3 = wts * zv;
        float v4 = wts;
#pragma unroll
        for (int off = 32; off >= 1; off >>= 1) {
            v0 += __shfl_down(v0, off, 64);
            v1 += __shfl_down(v1, off, 64);
            v2 += __shfl_down(v2, off, 64);
            v3 += __shfl_down(v3, off, 64);
            v4 += __shfl_down(v4, off, 64);
        }
        if (lane == 0) {
            s_red[wid][0] = v0;
            s_red[wid][1] = v1;
            s_red[wid][2] = v2;
            s_red[wid][3] = v3;
            s_red[wid][4] = v4;
        }
    }
    __syncthreads();

    if (t == 0) {
        float q0  = s_red[0][0] + s_red[1][0];
        float q1  = s_red[0][1] + s_red[1][1];
        float q2  = s_red[0][2] + s_red[1][2];
        float dep = s_red[0][3] + s_red[1][3];
        float acc = s_red[0][4] + s_red[1][4];
        float bg  = 1.0f - acc;
        float* o = out + (long long)ray * 5;
        o[0] = q0 + bg;
        o[1] = q1 + bg;
        o[2] = q2 + bg;
        o[3] = dep;
        o[4] = acc;
    }
}

extern "C" void kernel_launch(void* const* d_in, const int* in_sizes, int n_in,
                              void* d_out, int out_size, void* d_ws, size_t ws_size,
                              hipStream_t stream) {
    const float* points_feat = (const float*)d_in[0];
    const int*   indices     = (const int*)d_in[1];
    const float* dists       = (const float*)d_in[2];
    const float* w_rgb       = (const float*)d_in[3];
    const float* w_sigma     = (const float*)d_in[4];
    const float* delta       = (const float*)d_in[5];
    const float* z_vals      = (const float*)d_in[6];
    float* out = (float*)d_out;

    const int npts = in_sizes[0] / CF;
    const size_t need = (size_t)npts * sizeof(uint2);
    if (ws_size >= need) {
        hproj_kernel<<<(npts + 255) / 256, 256, 0, stream>>>(
            points_feat, w_rgb, w_sigma, (uint2*)d_ws, npts);
        pvr_main2<<<NRAYS / 2, TPB, 0, stream>>>(
            (const uint2*)d_ws, indices, dists, delta, z_vals, out);
    } else {
        pvr_fused_f32<<<NRAYS, 512, 0, stream>>>(
            points_feat, indices, dists, w_rgb, w_sigma, delta, z_vals, out);
    }
}